// Round 3
// baseline (9.633 us; speedup 1.0000x reference)
//
#include <hip/hip_runtime.h>
#include <hip/hip_bf16.h>

// Quanvolution (16-qubit circuit) collapses analytically to per-wire cosines:
// after RY-encoding the state is a real product state; the fixed RandomLayer
// acts on disjoint wire sets {3},{7},{11},{0,8},{14},{5,12},{2},{9,1}, so
// <Z_i> factorizes:
//   untouched / RZ wires: cos(x_i)
//   RY(p) wires (2,7):    cos(x_i + p)
//   RX(p) wires (3,14):   cos(p) * cos(x_i)
//   CNOT targets (8,12,1):cos(x_ctrl) * cos(x_tgt)   (controls unchanged)
// Then feat(4,1024) @ head_w^T + bias -> log_softmax.
//
// Parallel decomposition: grid = 4 blocks (one per batch image), block = 640
// threads = 10 waves, wave k owns logit k. Lane l recomputes patch l's 16
// features in-register (redundant across waves — free), loads its 64B slice
// of head_w row k, does a 16-FMA partial + 6-step shuffle reduce. One LDS
// scalar per wave, one barrier, thread 0 does the 10-way log_softmax.

__global__ __launch_bounds__(640)
void quanv_fused_kernel(const float* __restrict__ x,
                        const float* __restrict__ qp,
                        const float* __restrict__ hw,
                        const float* __restrict__ hb,
                        float* __restrict__ out) {
    __shared__ float sm[10];

    const int b    = blockIdx.x;            // batch image
    const int k    = threadIdx.x >> 6;      // logit id (wave id), 0..9
    const int lane = threadIdx.x & 63;      // patch id
    const int i    = lane >> 3;             // patch row
    const int j    = lane & 7;              // patch col

    // ---- per-patch analytic measurements (in registers) ----
    float a[16];
#pragma unroll
    for (int ch = 0; ch < 4; ++ch)
#pragma unroll
        for (int dy = 0; dy < 2; ++dy) {
            const float2 v = *(const float2*)
                (x + ((b * 4 + ch) * 16 + (i * 2 + dy)) * 16 + j * 2);
            a[ch * 4 + dy * 2 + 0] = v.x;
            a[ch * 4 + dy * 2 + 1] = v.y;
        }

    const float p0 = qp[0], p1 = qp[1], p3 = qp[3], p4 = qp[4]; // p2 (RZ) drops out

    float ca[16];
#pragma unroll
    for (int w = 0; w < 16; ++w) ca[w] = __cosf(a[w]);

    float m[16];
    m[0]  = ca[0];
    m[1]  = ca[9] * ca[1];
    m[2]  = __cosf(a[2] + p4);
    m[3]  = __cosf(p0) * ca[3];
    m[4]  = ca[4];
    m[5]  = ca[5];
    m[6]  = ca[6];
    m[7]  = __cosf(a[7] + p1);
    m[8]  = ca[0] * ca[8];
    m[9]  = ca[9];
    m[10] = ca[10];
    m[11] = ca[11];
    m[12] = ca[5] * ca[12];
    m[13] = ca[13];
    m[14] = __cosf(p3) * ca[14];
    m[15] = ca[15];

    // ---- wave k: partial dot with head_w row k, 64B slice per lane ----
    const float4* h4 = (const float4*)(hw + k * 1024 + lane * 16);
    float s = 0.0f;
#pragma unroll
    for (int q = 0; q < 4; ++q) {
        const float4 h = h4[q];
        s += m[q * 4 + 0] * h.x + m[q * 4 + 1] * h.y
           + m[q * 4 + 2] * h.z + m[q * 4 + 3] * h.w;
    }
#pragma unroll
    for (int off = 32; off > 0; off >>= 1) s += __shfl_down(s, off);

    if (lane == 0) sm[k] = s + hb[k];
    __syncthreads();

    // ---- thread 0: 10-way log_softmax, write out[b] ----
    if (threadIdx.x == 0) {
        float l[10];
#pragma unroll
        for (int q = 0; q < 10; ++q) l[q] = sm[q];
        float mx = l[0];
#pragma unroll
        for (int q = 1; q < 10; ++q) mx = fmaxf(mx, l[q]);
        float sum = 0.0f;
#pragma unroll
        for (int q = 0; q < 10; ++q) sum += __expf(l[q] - mx);
        const float lse = __logf(sum) + mx;
#pragma unroll
        for (int q = 0; q < 10; ++q) out[b * 10 + q] = l[q] - lse;
    }
}

extern "C" void kernel_launch(void* const* d_in, const int* in_sizes, int n_in,
                              void* d_out, int out_size, void* d_ws, size_t ws_size,
                              hipStream_t stream) {
    const float* x  = (const float*)d_in[0];   // (4,4,16,16)
    const float* qp = (const float*)d_in[1];   // (5,)
    const float* hw = (const float*)d_in[2];   // (10,1024)
    const float* hb = (const float*)d_in[3];   // (10,)
    float* out = (float*)d_out;                // (4,10)

    quanv_fused_kernel<<<4, 640, 0, stream>>>(x, qp, hw, hb, out);
}